// Round 11
// baseline (127.339 us; speedup 1.0000x reference)
//
#include <hip/hip_runtime.h>
#include <hip/hip_bf16.h>
#include <cstdint>

#define BATCH   32
#define NVARS   16
#define SAMPLES 4096
#define EDIM    128
#define NTOK    1016          // (4096-32)/4
#define KDIM    4096

typedef __bf16 bf8_t __attribute__((ext_vector_type(8)));
typedef float  f4_t  __attribute__((ext_vector_type(4)));

__device__ __forceinline__ void gload_lds16(const void* g, void* l) {
  __builtin_amdgcn_global_load_lds(
      (const __attribute__((address_space(1))) unsigned int*)g,
      (__attribute__((address_space(3))) unsigned int*)l, 16, 0, 0);
}

// ---------------------------------------------------------------------------
// prep_kernel = encode (blocks 0..511) + W_patch repack (blocks 512..639).
// encode: enc_p[b][phase][eblk][u(1024)][32] = floor(x@Ws+bs), bf16 (ints
// exact). Baked chunk swizzle phys=(c+(u>>1))&3.
// twp: WtF[kb][g(8)][lane(64)][t(8)] = B[kbase(kb)+quad*8+t][g*16+l15]
//   (kbase=(4*dlt+(s&3))*128+(s>>2)*32, kb=s*8+dlt) -> a GEMM wave's
//   B-fragment group is one coalesced 1KB global load straight to VGPRs.
// ---------------------------------------------------------------------------
__global__ __launch_bounds__(256) void prep_kernel(
    const float* __restrict__ x, const float* __restrict__ Ws,
    const float* __restrict__ bs, const float* __restrict__ Wp,
    __hip_bfloat16* __restrict__ enc, __hip_bfloat16* __restrict__ WtF)
{
  __shared__ float smem[32 * 132];
  int tid = threadIdx.x;

  if (blockIdx.x < 512) {
    // ------------------------- encode path -------------------------
    float (*xs)[256] = (float(*)[256])smem;
    int b  = blockIdx.x >> 4;
    int s0 = (blockIdx.x & 15) << 8;
    int u0 = s0 >> 2;

    {
      int col = (tid & 63) << 2;
      int v0  = tid >> 6;
#pragma unroll
      for (int j = 0; j < 4; ++j) {
        int v = v0 + j * 4;
        float4 t = *(const float4*)(x + (size_t)b * NVARS * SAMPLES
                                    + (size_t)v * SAMPLES + s0 + col);
        *(float4*)&xs[v][col] = t;
      }
    }

    int wv = tid >> 6, lane = tid & 63;
    int rlane = lane >> 2, c = lane & 3;
    int e = wv;
    int d0 = e * 32 + c * 8;

    float w[NVARS][8];
#pragma unroll
    for (int v = 0; v < NVARS; ++v) {
      float4 w0 = *(const float4*)&Ws[v * EDIM + d0];
      float4 w1 = *(const float4*)&Ws[v * EDIM + d0 + 4];
      w[v][0] = w0.x; w[v][1] = w0.y; w[v][2] = w0.z; w[v][3] = w0.w;
      w[v][4] = w1.x; w[v][5] = w1.y; w[v][6] = w1.z; w[v][7] = w1.w;
    }
    float bias[8];
    {
      float4 b0 = *(const float4*)&bs[d0];
      float4 b1 = *(const float4*)&bs[d0 + 4];
      bias[0] = b0.x; bias[1] = b0.y; bias[2] = b0.z; bias[3] = b0.w;
      bias[4] = b1.x; bias[5] = b1.y; bias[6] = b1.z; bias[7] = b1.w;
    }

    __syncthreads();

#pragma unroll
    for (int p = 0; p < 4; ++p)
#pragma unroll
      for (int uc = 0; uc < 4; ++uc) {
        int ur   = uc * 16 + rlane;
        int sloc = 4 * ur + p;
        float acc[8];
#pragma unroll
        for (int j = 0; j < 8; ++j) acc[j] = bias[j];
#pragma unroll
        for (int v = 0; v < NVARS; ++v) {
          float xv = xs[v][sloc];
#pragma unroll
          for (int j = 0; j < 8; ++j) acc[j] += xv * w[v][j];
        }
        union { unsigned short u[8]; uint4 q; } pk;
#pragma unroll
        for (int j = 0; j < 8; ++j)
          pk.u[j] = (unsigned short)(__float_as_uint(floorf(acc[j])) >> 16);
        int u    = u0 + ur;
        int phys = (c + (u >> 1)) & 3;
        size_t off = (((size_t)b * 4 + p) * 4 + e) * 32768 + (size_t)u * 32
                   + phys * 8;
        *(uint4*)(enc + off) = pk.q;
      }
  } else {
    // ------------------------- twp path -------------------------
    float (*ls)[132] = (float(*)[132])smem;
    int kb  = blockIdx.x - 512;
    int s   = kb >> 3, dlt = kb & 7;
    int kbase = (4 * dlt + (s & 3)) * 128 + (s >> 2) * 32;
#pragma unroll
    for (int r = 0; r < 16; ++r) {
      int idx = tid + r * 256;
      ls[idx >> 7][idx & 127] =
          Wp[(size_t)(kbase + (idx >> 7)) * EDIM + (idx & 127)];
    }
    __syncthreads();
    int g = tid >> 5, l5 = tid & 31;
#pragma unroll
    for (int h = 0; h < 2; ++h) {
      int lane = l5 + h * 32;
      int quad = lane >> 4, l15 = lane & 15;
      int n = g * 16 + l15;
      union { unsigned short u[8]; uint4 v; } pk;
#pragma unroll
      for (int t = 0; t < 8; ++t) {
        __hip_bfloat16 hh = __float2bfloat16(ls[quad * 8 + t][n]);
        pk.u[t] = *(unsigned short*)&hh;
      }
      *(uint4*)(WtF + (size_t)kb * 4096 + g * 512 + lane * 8) = pk.v;
    }
  }
}

// ---------------------------------------------------------------------------
// Stage 2 GEMM (R8 structure, verified): M=32512 N=128 K=4096. Grid 256
// (1 block/CU), 512 threads = 8 waves. Intra-block K-split-2: waves 0-3
// K[0,2048), waves 4-7 K[2048,4096); wave tile 64x64 (4x4 mfma 16x16x32).
// A: per-group plane-reuse LDS ring-2; B: fragment-major WtF -> VGPRs.
// R11 deltas vs R8: (1) bq depth-4 (issue-to-use ~4 compute bursts, covers
// L2/HBM-class latency; +32 VGPR, still 2 waves/SIMD); (2) reduction
// epilogue stride 17 (17 coprime 32 -> conflict-free).
// ---------------------------------------------------------------------------
__global__ __launch_bounds__(512, 2) void gemm_kernel(
    const __hip_bfloat16* __restrict__ enc,
    const __hip_bfloat16* __restrict__ WtF,
    const float* __restrict__ bp,
    float* __restrict__ out)
{
  __shared__ __align__(16) __hip_bfloat16 Apl[2][2][4608];  // 36 KB

  int tid  = threadIdx.x;
  int lane = tid & 63;
  int wv   = tid >> 6;               // 0..7
  int g    = wv >> 2;                // K-half
  int wq   = wv & 3;                 // quadrant of 128x128
  int b    = blockIdx.x >> 3;
  int t0   = (blockIdx.x & 7) << 7;
  int wm   = (wq >> 1) << 6;         // 0/64
  int wn   = (wq & 1) << 6;          // 0/64
  int quad = lane >> 4;
  int l15  = lane & 15;

  const __hip_bfloat16* encb = enc + (size_t)b * 524288;
  const __hip_bfloat16* bg   = WtF + (size_t)(wn >> 4) * 512 + lane * 8;

  f4_t acc[4][4];
  f4_t zero = {0.f, 0.f, 0.f, 0.f};
#pragma unroll
  for (int i = 0; i < 4; ++i)
#pragma unroll
    for (int j = 0; j < 4; ++j) acc[i][j] = zero;

  // stage global plane sp (rows t0..t0+143) into Apl[g][buf]; 9 units of
  // 512 elems; group wave wq loads {2wq, 2wq+1} + (wq==0 ? 8 : dup).
  auto stageA = [&](int sp, int buf) {
    const __hip_bfloat16* gp = encb
        + (size_t)((sp & 3) * 4 + (sp >> 2)) * 32768
        + (size_t)t0 * 32 + lane * 8;
    __hip_bfloat16* dst = &Apl[g][buf][0];
    int u3 = (wq == 0) ? 8 : (wq * 2 + 1);
    gload_lds16(gp + (size_t)(wq * 2) * 512,     dst + (wq * 2) * 512);
    gload_lds16(gp + (size_t)(wq * 2 + 1) * 512, dst + (wq * 2 + 1) * 512);
    gload_lds16(gp + (size_t)u3 * 512,           dst + u3 * 512);
  };

  auto loadB = [&](int kb, uint4* d) {
#pragma unroll
    for (int j = 0; j < 4; ++j)
      d[j] = *(const uint4*)(bg + (size_t)kb * 4096 + j * 512);
  };

  auto compute = [&](int abuf, int dlt, const uint4* bq) {
    const bf8_t* pA = (const bf8_t*)&Apl[g][abuf][0];
    int swzA = (quad + ((t0 + dlt + wm + l15) >> 1)) & 3;
    bf8_t af[4];
#pragma unroll
    for (int i = 0; i < 4; ++i)
      af[i] = pA[(dlt + wm + i * 16 + l15) * 4 + swzA];
#pragma unroll
    for (int mi = 0; mi < 4; ++mi)
#pragma unroll
      for (int ni = 0; ni < 4; ++ni)
        acc[mi][ni] = __builtin_amdgcn_mfma_f32_16x16x32_bf16(
            af[mi], __builtin_bit_cast(bf8_t, bq[ni]), acc[mi][ni], 0, 0, 0);
  };

  // prologue: own group's plane 0 (global plane g*8), B kb = g*64 .. +3
  stageA(g * 8, 0);
  asm volatile("s_waitcnt vmcnt(0)" ::: "memory");
  asm volatile("s_barrier" ::: "memory");

  uint4 bq[4][4];
  loadB(g * 64,     bq[0]);
  loadB(g * 64 + 1, bq[1]);
  loadB(g * 64 + 2, bq[2]);
  loadB(g * 64 + 3, bq[3]);

  for (int ss = 0; ss < 8; ++ss) {           // group-local supersteps
    if (ss < 7) stageA(g * 8 + ss + 1, (ss + 1) & 1);
#pragma unroll
    for (int d = 0; d < 8; ++d) {
      int kl = ss * 8 + d;                   // group-local kb 0..63
      compute(ss & 1, d, bq[kl & 3]);
      if (kl < 60) loadB(g * 64 + kl + 4, bq[kl & 3]);
    }
    asm volatile("s_barrier" ::: "memory");  // wave's own stageA drained by
  }                                          // its newer B-load vmcnt waits

  // ---- K-half reduction (group1 -> group0 via LDS) + fused epilogue ----
  // stride-17 float rows: 17 coprime to 32 -> conflict-free LDS access.
  float* rb = (float*)&Apl[0][0][0];         // 4352 floats = 17 KB per round
  int widx = (wq * 64 + lane) * 17;
  float bias[4];
#pragma unroll
  for (int ni = 0; ni < 4; ++ni) bias[ni] = bp[wn + ni * 16 + l15];

#pragma unroll
  for (int mi = 0; mi < 4; ++mi) {
    __syncthreads();
    if (g == 1) {
#pragma unroll
      for (int ni = 0; ni < 4; ++ni)
#pragma unroll
        for (int r = 0; r < 4; ++r)
          rb[widx + ni * 4 + r] = acc[mi][ni][r];
    }
    __syncthreads();
    if (g == 0) {
#pragma unroll
      for (int ni = 0; ni < 4; ++ni)
#pragma unroll
        for (int r = 0; r < 4; ++r) {
          int t = t0 + wm + mi * 16 + quad * 4 + r;
          if (t < NTOK) {
            int n = wn + ni * 16 + l15;
            out[((size_t)b * NTOK + t) * EDIM + n] =
                floorf(acc[mi][ni][r] + rb[widx + ni * 4 + r] + bias[ni]);
          }
        }
    }
  }
}

// ---------------------------------------------------------------------------
extern "C" void kernel_launch(void* const* d_in, const int* in_sizes, int n_in,
                              void* d_out, int out_size, void* d_ws, size_t ws_size,
                              hipStream_t stream) {
  const float* x  = (const float*)d_in[0];
  const float* Ws = (const float*)d_in[1];
  const float* bs = (const float*)d_in[2];
  const float* Wp = (const float*)d_in[3];
  const float* bp = (const float*)d_in[4];
  float* out = (float*)d_out;

  __hip_bfloat16* enc = (__hip_bfloat16*)d_ws;   // 32 MB, plane-split layout
  __hip_bfloat16* WtF = (__hip_bfloat16*)((char*)d_ws +
                        (size_t)BATCH * SAMPLES * EDIM * sizeof(__hip_bfloat16));

  prep_kernel<<<512 + 128, 256, 0, stream>>>(x, Ws, bs, Wp, enc, WtF);
  gemm_kernel<<<BATCH * 8, 512, 0, stream>>>(enc, WtF, bp, out);
}

// Round 12
// 120.990 us; speedup vs baseline: 1.0525x; 1.0525x over previous
//
#include <hip/hip_runtime.h>
#include <hip/hip_bf16.h>
#include <cstdint>

#define BATCH   32
#define NVARS   16
#define SAMPLES 4096
#define EDIM    128
#define NTOK    1016          // (4096-32)/4
#define KDIM    4096

typedef __bf16 bf8_t __attribute__((ext_vector_type(8)));
typedef float  f4_t  __attribute__((ext_vector_type(4)));

__device__ __forceinline__ void gload_lds16(const void* g, void* l) {
  __builtin_amdgcn_global_load_lds(
      (const __attribute__((address_space(1))) unsigned int*)g,
      (__attribute__((address_space(3))) unsigned int*)l, 16, 0, 0);
}

// ---------------------------------------------------------------------------
// prep_kernel = encode (blocks 0..511) + W_patch repack (blocks 512..639).
// encode: enc_p[b][phase][eblk][u(1024)][32] = floor(x@Ws+bs), bf16 (ints
// exact). Baked chunk swizzle phys=(c+(u>>1))&3.
// twp: WtF[kb][g(8)][lane(64)][t(8)] = B[kbase(kb)+quad*8+t][g*16+l15]
//   (kbase=(4*dlt+(s&3))*128+(s>>2)*32, kb=s*8+dlt) -> a GEMM wave's
//   B-fragment group is one coalesced 1KB global load straight to VGPRs.
// ---------------------------------------------------------------------------
__global__ __launch_bounds__(256) void prep_kernel(
    const float* __restrict__ x, const float* __restrict__ Ws,
    const float* __restrict__ bs, const float* __restrict__ Wp,
    __hip_bfloat16* __restrict__ enc, __hip_bfloat16* __restrict__ WtF)
{
  __shared__ float smem[32 * 132];
  int tid = threadIdx.x;

  if (blockIdx.x < 512) {
    // ------------------------- encode path -------------------------
    float (*xs)[256] = (float(*)[256])smem;
    int b  = blockIdx.x >> 4;
    int s0 = (blockIdx.x & 15) << 8;
    int u0 = s0 >> 2;

    {
      int col = (tid & 63) << 2;
      int v0  = tid >> 6;
#pragma unroll
      for (int j = 0; j < 4; ++j) {
        int v = v0 + j * 4;
        float4 t = *(const float4*)(x + (size_t)b * NVARS * SAMPLES
                                    + (size_t)v * SAMPLES + s0 + col);
        *(float4*)&xs[v][col] = t;
      }
    }

    int wv = tid >> 6, lane = tid & 63;
    int rlane = lane >> 2, c = lane & 3;
    int e = wv;
    int d0 = e * 32 + c * 8;

    float w[NVARS][8];
#pragma unroll
    for (int v = 0; v < NVARS; ++v) {
      float4 w0 = *(const float4*)&Ws[v * EDIM + d0];
      float4 w1 = *(const float4*)&Ws[v * EDIM + d0 + 4];
      w[v][0] = w0.x; w[v][1] = w0.y; w[v][2] = w0.z; w[v][3] = w0.w;
      w[v][4] = w1.x; w[v][5] = w1.y; w[v][6] = w1.z; w[v][7] = w1.w;
    }
    float bias[8];
    {
      float4 b0 = *(const float4*)&bs[d0];
      float4 b1 = *(const float4*)&bs[d0 + 4];
      bias[0] = b0.x; bias[1] = b0.y; bias[2] = b0.z; bias[3] = b0.w;
      bias[4] = b1.x; bias[5] = b1.y; bias[6] = b1.z; bias[7] = b1.w;
    }

    __syncthreads();

#pragma unroll
    for (int p = 0; p < 4; ++p)
#pragma unroll
      for (int uc = 0; uc < 4; ++uc) {
        int ur   = uc * 16 + rlane;
        int sloc = 4 * ur + p;
        float acc[8];
#pragma unroll
        for (int j = 0; j < 8; ++j) acc[j] = bias[j];
#pragma unroll
        for (int v = 0; v < NVARS; ++v) {
          float xv = xs[v][sloc];
#pragma unroll
          for (int j = 0; j < 8; ++j) acc[j] += xv * w[v][j];
        }
        union { unsigned short u[8]; uint4 q; } pk;
#pragma unroll
        for (int j = 0; j < 8; ++j)
          pk.u[j] = (unsigned short)(__float_as_uint(floorf(acc[j])) >> 16);
        int u    = u0 + ur;
        int phys = (c + (u >> 1)) & 3;
        size_t off = (((size_t)b * 4 + p) * 4 + e) * 32768 + (size_t)u * 32
                   + phys * 8;
        *(uint4*)(enc + off) = pk.q;
      }
  } else {
    // ------------------------- twp path -------------------------
    float (*ls)[132] = (float(*)[132])smem;
    int kb  = blockIdx.x - 512;
    int s   = kb >> 3, dlt = kb & 7;
    int kbase = (4 * dlt + (s & 3)) * 128 + (s >> 2) * 32;
#pragma unroll
    for (int r = 0; r < 16; ++r) {
      int idx = tid + r * 256;
      ls[idx >> 7][idx & 127] =
          Wp[(size_t)(kbase + (idx >> 7)) * EDIM + (idx & 127)];
    }
    __syncthreads();
    int g = tid >> 5, l5 = tid & 31;
#pragma unroll
    for (int h = 0; h < 2; ++h) {
      int lane = l5 + h * 32;
      int quad = lane >> 4, l15 = lane & 15;
      int n = g * 16 + l15;
      union { unsigned short u[8]; uint4 v; } pk;
#pragma unroll
      for (int t = 0; t < 8; ++t) {
        __hip_bfloat16 hh = __float2bfloat16(ls[quad * 8 + t][n]);
        pk.u[t] = *(unsigned short*)&hh;
      }
      *(uint4*)(WtF + (size_t)kb * 4096 + g * 512 + lane * 8) = pk.v;
    }
  }
}

// ---------------------------------------------------------------------------
// Stage 2 GEMM (R8 structure = verified best of 5 variants): M=32512 N=128
// K=4096. Grid 256 (1 block/CU), 512 threads = 8 waves. Intra-block
// K-split-2: waves 0-3 K[0,2048), waves 4-7 K[2048,4096); wave tile 64x64
// (4x4 mfma 16x16x32). A: per-group plane-reuse LDS ring-2; B: fragment-
// major WtF -> VGPRs, depth-2 (depth-4 regressed: VGPR pressure, R11).
// R12 delta vs R8: reduction epilogue stride 16 -> 17 floats (17 coprime
// 32 -> conflict-free; R9 measured 1.46M conflict-cycles at stride 16).
// ---------------------------------------------------------------------------
__global__ __launch_bounds__(512, 2) void gemm_kernel(
    const __hip_bfloat16* __restrict__ enc,
    const __hip_bfloat16* __restrict__ WtF,
    const float* __restrict__ bp,
    float* __restrict__ out)
{
  __shared__ __align__(16) __hip_bfloat16 Apl[2][2][4608];  // 36 KB

  int tid  = threadIdx.x;
  int lane = tid & 63;
  int wv   = tid >> 6;               // 0..7
  int g    = wv >> 2;                // K-half
  int wq   = wv & 3;                 // quadrant of 128x128
  int b    = blockIdx.x >> 3;
  int t0   = (blockIdx.x & 7) << 7;
  int wm   = (wq >> 1) << 6;         // 0/64
  int wn   = (wq & 1) << 6;          // 0/64
  int quad = lane >> 4;
  int l15  = lane & 15;

  const __hip_bfloat16* encb = enc + (size_t)b * 524288;
  const __hip_bfloat16* bg   = WtF + (size_t)(wn >> 4) * 512 + lane * 8;

  f4_t acc[4][4];
  f4_t zero = {0.f, 0.f, 0.f, 0.f};
#pragma unroll
  for (int i = 0; i < 4; ++i)
#pragma unroll
    for (int j = 0; j < 4; ++j) acc[i][j] = zero;

  // stage global plane sp (rows t0..t0+143) into Apl[g][buf]; 9 units of
  // 512 elems; group wave wq loads {2wq, 2wq+1} + (wq==0 ? 8 : dup).
  auto stageA = [&](int sp, int buf) {
    const __hip_bfloat16* gp = encb
        + (size_t)((sp & 3) * 4 + (sp >> 2)) * 32768
        + (size_t)t0 * 32 + lane * 8;
    __hip_bfloat16* dst = &Apl[g][buf][0];
    int u3 = (wq == 0) ? 8 : (wq * 2 + 1);
    gload_lds16(gp + (size_t)(wq * 2) * 512,     dst + (wq * 2) * 512);
    gload_lds16(gp + (size_t)(wq * 2 + 1) * 512, dst + (wq * 2 + 1) * 512);
    gload_lds16(gp + (size_t)u3 * 512,           dst + u3 * 512);
  };

  auto loadB = [&](int kb, uint4* d) {
#pragma unroll
    for (int j = 0; j < 4; ++j)
      d[j] = *(const uint4*)(bg + (size_t)kb * 4096 + j * 512);
  };

  auto compute = [&](int abuf, int dlt, const uint4* bq) {
    const bf8_t* pA = (const bf8_t*)&Apl[g][abuf][0];
    int swzA = (quad + ((t0 + dlt + wm + l15) >> 1)) & 3;
    bf8_t af[4];
#pragma unroll
    for (int i = 0; i < 4; ++i)
      af[i] = pA[(dlt + wm + i * 16 + l15) * 4 + swzA];
#pragma unroll
    for (int mi = 0; mi < 4; ++mi)
#pragma unroll
      for (int ni = 0; ni < 4; ++ni)
        acc[mi][ni] = __builtin_amdgcn_mfma_f32_16x16x32_bf16(
            af[mi], __builtin_bit_cast(bf8_t, bq[ni]), acc[mi][ni], 0, 0, 0);
  };

  // prologue: own group's plane 0 (global plane g*8), B kb = g*64, g*64+1
  stageA(g * 8, 0);
  asm volatile("s_waitcnt vmcnt(0)" ::: "memory");
  asm volatile("s_barrier" ::: "memory");

  uint4 bq[2][4];
  loadB(g * 64, bq[0]);
  loadB(g * 64 + 1, bq[1]);

  for (int ss = 0; ss < 8; ++ss) {           // group-local supersteps
    if (ss < 7) stageA(g * 8 + ss + 1, (ss + 1) & 1);
#pragma unroll
    for (int d = 0; d < 8; ++d) {
      int kl = ss * 8 + d;                   // group-local kb 0..63
      compute(ss & 1, d, bq[d & 1]);
      if (kl < 62) loadB(g * 64 + kl + 2, bq[d & 1]);
    }
    asm volatile("s_barrier" ::: "memory");  // wave's own stageA drained by
  }                                          // its newer B-load vmcnt waits

  // ---- K-half reduction (group1 -> group0 via LDS) + fused epilogue ----
  // stride-17 float rows: 17 coprime to 32 -> conflict-free LDS access.
  float* rb = (float*)&Apl[0][0][0];         // 4352 floats = 17 KB per round
  int widx = (wq * 64 + lane) * 17;
  float bias[4];
#pragma unroll
  for (int ni = 0; ni < 4; ++ni) bias[ni] = bp[wn + ni * 16 + l15];

#pragma unroll
  for (int mi = 0; mi < 4; ++mi) {
    __syncthreads();
    if (g == 1) {
#pragma unroll
      for (int ni = 0; ni < 4; ++ni)
#pragma unroll
        for (int r = 0; r < 4; ++r)
          rb[widx + ni * 4 + r] = acc[mi][ni][r];
    }
    __syncthreads();
    if (g == 0) {
#pragma unroll
      for (int ni = 0; ni < 4; ++ni)
#pragma unroll
        for (int r = 0; r < 4; ++r) {
          int t = t0 + wm + mi * 16 + quad * 4 + r;
          if (t < NTOK) {
            int n = wn + ni * 16 + l15;
            out[((size_t)b * NTOK + t) * EDIM + n] =
                floorf(acc[mi][ni][r] + rb[widx + ni * 4 + r] + bias[ni]);
          }
        }
    }
  }
}

// ---------------------------------------------------------------------------
extern "C" void kernel_launch(void* const* d_in, const int* in_sizes, int n_in,
                              void* d_out, int out_size, void* d_ws, size_t ws_size,
                              hipStream_t stream) {
  const float* x  = (const float*)d_in[0];
  const float* Ws = (const float*)d_in[1];
  const float* bs = (const float*)d_in[2];
  const float* Wp = (const float*)d_in[3];
  const float* bp = (const float*)d_in[4];
  float* out = (float*)d_out;

  __hip_bfloat16* enc = (__hip_bfloat16*)d_ws;   // 32 MB, plane-split layout
  __hip_bfloat16* WtF = (__hip_bfloat16*)((char*)d_ws +
                        (size_t)BATCH * SAMPLES * EDIM * sizeof(__hip_bfloat16));

  prep_kernel<<<512 + 128, 256, 0, stream>>>(x, Ws, bs, Wp, enc, WtF);
  gemm_kernel<<<BATCH * 8, 512, 0, stream>>>(enc, WtF, bp, out);
}